// Round 4
// baseline (327.239 us; speedup 1.0000x reference)
//
#include <hip/hip_runtime.h>
#include <hip/hip_bf16.h>
#include <math.h>

// Problem constants (fixed shapes from setup_inputs)
#define B_    2
#define N_    2048
#define D_    1024
#define H_    16
#define ENC_  8
#define HD_   64
#define EPS_  1e-5f
#define M_    (B_ * N_)        // 4096 rows for all GEMMs

typedef __bf16 bf16x8 __attribute__((ext_vector_type(8)));
typedef float  f32x4  __attribute__((ext_vector_type(4)));

#define MB(x) ((size_t)(x) * 1024 * 1024)

// Async global->LDS 16B copy. HW writes lds_base + lane*16; lds ptr must be
// wave-uniform and the lane->global mapping must match that contiguity.
__device__ __forceinline__ void gld16(const __bf16* g, __bf16* l) {
    __builtin_amdgcn_global_load_lds(
        (const __attribute__((address_space(1))) void*)g,
        (__attribute__((address_space(3))) void*)l,
        16, 0, 0);
}

// ---------------------------------------------------------------------------
// bf16 MFMA GEMM, B pre-transposed: C[M,Nn] = A[M,K] @ Bt[Nn,K]^T.
// m97 structure: 128x128 tile, BK=32, 4 waves (2x2), each wave 4x4 MFMA
// 16x16x32 tiles, global_load_lds width-16 staging, 2-barrier K-loop.
// ---------------------------------------------------------------------------
template <typename OutT>
__global__ __launch_bounds__(256) void gemm_bt(
    const __bf16* __restrict__ A, const __bf16* __restrict__ Bt,
    OutT* __restrict__ C, int K, int lda, int aoff, int ldc)
{
    __shared__ __bf16 As[128 * 32];   // [row][k], 64 B rows
    __shared__ __bf16 Bs[128 * 32];   // [col][k]

    const int tid  = threadIdx.x;
    const int w    = tid >> 6;
    const int lane = tid & 63;
    const int lrow = lane & 15;
    const int quad = lane >> 4;
    const int wr   = w >> 1;           // wave row 0..1
    const int wc   = w & 1;            // wave col 0..1

    const int bm = blockIdx.y * 128;
    const int bn = blockIdx.x * 128;

    const int sr = lane >> 2;
    const int sc = (lane & 3) * 8;
    const __bf16* Ag0 = A  + (size_t)(bm +      w * 16 + sr) * lda + aoff + sc;
    const __bf16* Ag1 = A  + (size_t)(bm + 64 + w * 16 + sr) * lda + aoff + sc;
    const __bf16* Bg0 = Bt + (size_t)(bn +      w * 16 + sr) * K + sc;
    const __bf16* Bg1 = Bt + (size_t)(bn + 64 + w * 16 + sr) * K + sc;
    __bf16* Al0 = &As[w * 512];
    __bf16* Al1 = &As[2048 + w * 512];
    __bf16* Bl0 = &Bs[w * 512];
    __bf16* Bl1 = &Bs[2048 + w * 512];

    f32x4 acc[4][4];
    #pragma unroll
    for (int i = 0; i < 4; ++i)
        #pragma unroll
        for (int j = 0; j < 4; ++j) acc[i][j] = (f32x4){0.f, 0.f, 0.f, 0.f};

    for (int k0 = 0; k0 < K; k0 += 32) {
        gld16(Ag0 + k0, Al0);
        gld16(Ag1 + k0, Al1);
        gld16(Bg0 + k0, Bl0);
        gld16(Bg1 + k0, Bl1);
        __syncthreads();   // drains vmcnt -> LDS data visible

        bf16x8 af[4], bf[4];
        #pragma unroll
        for (int rt = 0; rt < 4; ++rt)
            af[rt] = *(const bf16x8*)&As[(wr * 64 + rt * 16 + lrow) * 32 + quad * 8];
        #pragma unroll
        for (int ct = 0; ct < 4; ++ct)
            bf[ct] = *(const bf16x8*)&Bs[(wc * 64 + ct * 16 + lrow) * 32 + quad * 8];

        #pragma unroll
        for (int rt = 0; rt < 4; ++rt)
            #pragma unroll
            for (int ct = 0; ct < 4; ++ct)
                acc[rt][ct] = __builtin_amdgcn_mfma_f32_16x16x32_bf16(
                    af[rt], bf[ct], acc[rt][ct], 0, 0, 0);
        __syncthreads();
    }

    #pragma unroll
    for (int rt = 0; rt < 4; ++rt)
        #pragma unroll
        for (int ct = 0; ct < 4; ++ct)
            #pragma unroll
            for (int r = 0; r < 4; ++r) {
                const int row = bm + wr * 64 + rt * 16 + quad * 4 + r;
                const int col = bn + wc * 64 + ct * 16 + lrow;
                C[(size_t)row * ldc + col] = (OutT)acc[rt][ct][r];
            }
}

// ---------------------------------------------------------------------------
__global__ __launch_bounds__(256) void f32_to_bf16(
    const float* __restrict__ src, __bf16* __restrict__ dst)
{
    const size_t i = ((size_t)blockIdx.x * 256 + threadIdx.x) * 8;
    float4 a = *(const float4*)&src[i];
    float4 b = *(const float4*)&src[i + 4];
    bf16x8 o = {(__bf16)a.x, (__bf16)a.y, (__bf16)a.z, (__bf16)a.w,
                (__bf16)b.x, (__bf16)b.y, (__bf16)b.z, (__bf16)b.w};
    *(bf16x8*)&dst[i] = o;
}

// ---------------------------------------------------------------------------
// Weight convert + transpose: W[K,Nn] fp32 -> Wt[Nn,K] bf16. 64x64 LDS tiles.
// ---------------------------------------------------------------------------
__global__ __launch_bounds__(256) void wt_conv(
    const float* __restrict__ W, __bf16* __restrict__ Wt, int K, int Nn)
{
    __shared__ __bf16 t[64][72];
    const int kb = blockIdx.y * 64;
    const int nb = blockIdx.x * 64;
    {
        const int kl = threadIdx.x >> 2;
        const int c0 = (threadIdx.x & 3) * 16;
        const float* src = W + (size_t)(kb + kl) * Nn + nb + c0;
        #pragma unroll
        for (int u = 0; u < 4; ++u) {
            float4 f = *(const float4*)&src[u * 4];
            t[c0 + u * 4 + 0][kl] = (__bf16)f.x;
            t[c0 + u * 4 + 1][kl] = (__bf16)f.y;
            t[c0 + u * 4 + 2][kl] = (__bf16)f.z;
            t[c0 + u * 4 + 3][kl] = (__bf16)f.w;
        }
    }
    __syncthreads();
    {
        const int nl  = threadIdx.x >> 2;
        const int k0c = (threadIdx.x & 3) * 16;
        __bf16* dst = Wt + (size_t)(nb + nl) * K + kb + k0c;
        *(bf16x8*)&dst[0] = *(const bf16x8*)&t[nl][k0c];
        *(bf16x8*)&dst[8] = *(const bf16x8*)&t[nl][k0c + 8];
    }
}

// ---------------------------------------------------------------------------
// Fused RoPE + RMSNorm. Reads bf16 fused qkv [4096][3072] (q col 0, k col
// 1024), writes bf16 head-major (B,H,N,HD). One wave per row.
// ---------------------------------------------------------------------------
__global__ __launch_bounds__(256) void rope_rms_bf(
    const __bf16* __restrict__ qkv,
    const float* __restrict__ cs, const float* __restrict__ sn,
    __bf16* __restrict__ qbf, __bf16* __restrict__ kbf)
{
    const int row  = blockIdx.x * 4 + (threadIdx.x >> 6);  // (b*N + n)*H + h
    const int lane = threadIdx.x & 63;
    const int n    = (row >> 4) & (N_ - 1);
    const int b    = row >> 15;
    const int h    = row & 15;
    const int p    = lane >> 1;

    const float c = cs[n * (HD_ / 2) + p];
    const float s = sn[n * (HD_ / 2) + p];
    const size_t ibase = (size_t)(b * N_ + n) * 3072 + h * HD_ + lane;
    const size_t obase = ((size_t)(b * H_ + h) * N_ + n) * HD_ + lane;
    const bool odd = (lane & 1);

    {
        float val = (float)qkv[ibase];                  // q
        float partner = __shfl_xor(val, 1, 64);
        float r = odd ? fmaf(partner, s, val * c)
                      : (val * c - partner * s);
        float ss = r * r;
        #pragma unroll
        for (int off = 1; off < 64; off <<= 1) ss += __shfl_xor(ss, off, 64);
        qbf[obase] = (__bf16)(r * rsqrtf(ss * (1.0f / 64.0f) + EPS_));
    }
    {
        float val = (float)qkv[ibase + 1024];           // k
        float partner = __shfl_xor(val, 1, 64);
        float r = odd ? fmaf(partner, s, val * c)
                      : (val * c - partner * s);
        float ss = r * r;
        #pragma unroll
        for (int off = 1; off < 64; off <<= 1) ss += __shfl_xor(ss, off, 64);
        kbf[obase] = (__bf16)(r * rsqrtf(ss * (1.0f / 64.0f) + EPS_));
    }
}

// ---------------------------------------------------------------------------
// V transpose: bf16 v slice of qkv (cols 2048..3071) -> bf16 (B,H,HD,N).
// ---------------------------------------------------------------------------
__global__ __launch_bounds__(256) void vconv(
    const __bf16* __restrict__ qkv, __bf16* __restrict__ vt)
{
    __shared__ __bf16 tile[64][72];
    const int bh = blockIdx.y;
    const int b  = bh >> 4, h = bh & 15;
    const int n0 = blockIdx.x * 64;
    {
        const int nl = threadIdx.x >> 2;
        const int d0 = (threadIdx.x & 3) * 16;
        const __bf16* src = qkv + (size_t)(b * N_ + n0 + nl) * 3072 + 2048 + h * HD_ + d0;
        bf16x8 v0 = *(const bf16x8*)&src[0];
        bf16x8 v1 = *(const bf16x8*)&src[8];
        #pragma unroll
        for (int e = 0; e < 8; ++e) {
            tile[d0 + e][nl]     = v0[e];
            tile[d0 + 8 + e][nl] = v1[e];
        }
    }
    __syncthreads();
    {
        const int dl = threadIdx.x >> 2;
        const int nc = (threadIdx.x & 3) * 16;
        __bf16* dst = vt + ((size_t)(bh * HD_ + dl)) * N_ + n0 + nc;
        *(bf16x8*)&dst[0] = *(const bf16x8*)&tile[dl][nc];
        *(bf16x8*)&dst[8] = *(const bf16x8*)&tile[dl][nc + 8];
    }
}

// ---------------------------------------------------------------------------
// MFMA flash attention v2 (bf16 in, bf16 out).
// Per wave: 32 query rows of one (b,h); 32-key tiles.
// R4 changes vs R3:
//  - register double-buffered K/V prefetch (tile t+1 loads issued before
//    computing tile t; unroll-by-2 ping-pong -> vmcnt never drains)
//  - Plds rows padded 32->36 (stride 18 words: 18q distinct mod 32 for all
//    q in [0,16) -> conflict-free ds_write_u16 / ds_read_b128)
//  - causal mask only evaluated on a dec wave's LAST tile (wave-uniform
//    branch); all other tiles take the unmasked exp path
// ---------------------------------------------------------------------------
__global__ __launch_bounds__(256) void attn_mfma(
    const __bf16* __restrict__ qbf, const __bf16* __restrict__ kbf,
    const __bf16* __restrict__ vtbf, __bf16* __restrict__ o)
{
    __shared__ __bf16 Plds[4][2][16][36];   // padded: conflict-free

    const int w    = threadIdx.x >> 6;
    const int lane = threadIdx.x & 63;
    const int lrow = lane & 15;
    const int quad = lane >> 4;

    const int bh = blockIdx.y;          // 0..31
    const int b  = bh >> 4, h = bh & 15;
    const bool enc = (h < ENC_);
    const int i0 = blockIdx.x * 128 + w * 32;

    const __bf16* qbase = qbf  + (size_t)bh * N_ * HD_;
    const __bf16* kbase = kbf  + (size_t)bh * N_ * HD_;
    const __bf16* vbase = vtbf + (size_t)bh * HD_ * N_;

    bf16x8 qf[2][2];
    #pragma unroll
    for (int qt = 0; qt < 2; ++qt)
        #pragma unroll
        for (int kc = 0; kc < 2; ++kc)
            qf[qt][kc] = *(const bf16x8*)
                &qbase[(size_t)(i0 + qt * 16 + lrow) * HD_ + kc * 32 + quad * 8];

    const f32x4 zero = {0.f, 0.f, 0.f, 0.f};
    f32x4 oacc[2][4];
    #pragma unroll
    for (int qt = 0; qt < 2; ++qt)
        #pragma unroll
        for (int c = 0; c < 4; ++c) oacc[qt][c] = zero;
    float lsum[2][4] = {};

    const float KS = 0.125f * 1.4426950408889634f;
    const float KO = -8.0f  * 1.4426950408889634f;

    const int ntiles = (enc ? N_ : (i0 + 32)) >> 5;

    // Lane-constant load base pointers (j0 advances them linearly)
    const __bf16* kptr0 = kbase + (size_t)lrow * HD_ + quad * 8;
    const __bf16* vptr0 = vbase + (size_t)lrow * N_ + quad * 8;

    auto load_tile = [&](int j0, bf16x8* kf, bf16x8* vf) {
        const __bf16* kp = kptr0 + (size_t)j0 * HD_;
        kf[0] = *(const bf16x8*)(kp);
        kf[1] = *(const bf16x8*)(kp + 32);
        kf[2] = *(const bf16x8*)(kp + 16 * HD_);
        kf[3] = *(const bf16x8*)(kp + 16 * HD_ + 32);
        const __bf16* vp = vptr0 + j0;
        vf[0] = *(const bf16x8*)(vp);
        vf[1] = *(const bf16x8*)(vp + 16 * N_);
        vf[2] = *(const bf16x8*)(vp + 32 * N_);
        vf[3] = *(const bf16x8*)(vp + 48 * N_);
    };

    auto compute_tile = [&](int j0, const bf16x8* kf, const bf16x8* vf,
                            bool masked) {
        #pragma unroll
        for (int qt = 0; qt < 2; ++qt) {
            f32x4 s0 = zero, s1 = zero;
            s0 = __builtin_amdgcn_mfma_f32_16x16x32_bf16(qf[qt][0], kf[0], s0, 0, 0, 0);
            s0 = __builtin_amdgcn_mfma_f32_16x16x32_bf16(qf[qt][1], kf[1], s0, 0, 0, 0);
            s1 = __builtin_amdgcn_mfma_f32_16x16x32_bf16(qf[qt][0], kf[2], s1, 0, 0, 0);
            s1 = __builtin_amdgcn_mfma_f32_16x16x32_bf16(qf[qt][1], kf[3], s1, 0, 0, 0);
            if (masked) {
                #pragma unroll
                for (int r = 0; r < 4; ++r) {
                    const int i  = i0 + qt * 16 + quad * 4 + r;
                    const int jA = j0 + lrow;
                    const int jB = j0 + 16 + lrow;
                    float pA = (jA <= i) ? exp2f(fmaf(s0[r], KS, KO)) : 0.f;
                    float pB = (jB <= i) ? exp2f(fmaf(s1[r], KS, KO)) : 0.f;
                    lsum[qt][r] += pA + pB;
                    Plds[w][qt][quad * 4 + r][lrow]      = (__bf16)pA;
                    Plds[w][qt][quad * 4 + r][lrow + 16] = (__bf16)pB;
                }
            } else {
                #pragma unroll
                for (int r = 0; r < 4; ++r) {
                    float pA = exp2f(fmaf(s0[r], KS, KO));
                    float pB = exp2f(fmaf(s1[r], KS, KO));
                    lsum[qt][r] += pA + pB;
                    Plds[w][qt][quad * 4 + r][lrow]      = (__bf16)pA;
                    Plds[w][qt][quad * 4 + r][lrow + 16] = (__bf16)pB;
                }
            }
        }
        #pragma unroll
        for (int qt = 0; qt < 2; ++qt) {
            bf16x8 pf = *(const bf16x8*)&Plds[w][qt][lrow][quad * 8];
            #pragma unroll
            for (int c = 0; c < 4; ++c)
                oacc[qt][c] = __builtin_amdgcn_mfma_f32_16x16x32_bf16(
                    pf, vf[c], oacc[qt][c], 0, 0, 0);
        }
    };

    bf16x8 kA[4], vA[4], kB[4], vB[4];
    load_tile(0, kA, vA);
    int t = 0;
    const bool dec = !enc;
    for (;;) {
        load_tile((t + 1 < ntiles) ? (t + 1) * 32 : 0, kB, vB);
        compute_tile(t * 32, kA, vA, dec && (t == ntiles - 1));
        if (++t == ntiles) break;
        load_tile((t + 1 < ntiles) ? (t + 1) * 32 : 0, kA, vA);
        compute_tile(t * 32, kB, vB, dec && (t == ntiles - 1));
        if (++t == ntiles) break;
    }

    #pragma unroll
    for (int qt = 0; qt < 2; ++qt)
        #pragma unroll
        for (int r = 0; r < 4; ++r) {
            float s = lsum[qt][r];
            s += __shfl_xor(s, 1, 64);
            s += __shfl_xor(s, 2, 64);
            s += __shfl_xor(s, 4, 64);
            s += __shfl_xor(s, 8, 64);
            lsum[qt][r] = 1.0f / s;
        }

    #pragma unroll
    for (int qt = 0; qt < 2; ++qt)
        #pragma unroll
        for (int c = 0; c < 4; ++c)
            #pragma unroll
            for (int r = 0; r < 4; ++r) {
                const int i = i0 + qt * 16 + quad * 4 + r;
                o[(size_t)(b * N_ + i) * D_ + h * HD_ + c * 16 + lrow] =
                    (__bf16)(oacc[qt][c][r] * lsum[qt][r]);
            }
}

// ---------------------------------------------------------------------------
extern "C" void kernel_launch(void* const* d_in, const int* in_sizes, int n_in,
                              void* d_out, int out_size, void* d_ws, size_t ws_size,
                              hipStream_t stream)
{
    const float* x   = (const float*)d_in[0];
    const float* cs  = (const float*)d_in[1];
    const float* sn  = (const float*)d_in[2];
    const float* Wq  = (const float*)d_in[3];
    const float* Wk  = (const float*)d_in[4];
    const float* Wv  = (const float*)d_in[5];
    const float* Woe = (const float*)d_in[6];
    const float* Wod = (const float*)d_in[7];

    float* enc_out = (float*)d_out;
    float* dec_out = enc_out + (size_t)M_ * D_;

    // Workspace (57 MB), stream-ordered aliasing:
    //   [0,8)    xbf      -> reused as vtbf after QKV GEMM
    //   [8,14)   wqkv_t   (3072 x 1024 bf16)
    //   [14,16)  woe_t    (1024 x 1024 bf16)
    //   [16,17)  wod_t    (1024 x 512 bf16)
    //   [17,41)  qkv      (4096 x 3072 bf16) -> reused as obuf
    //   [41,49)  qbf head-major
    //   [49,57)  kbf head-major
    char* ws = (char*)d_ws;
    __bf16* xbf    = (__bf16*)(ws);
    __bf16* wqkv_t = (__bf16*)(ws + MB(8));
    __bf16* woe_t  = (__bf16*)(ws + MB(14));
    __bf16* wod_t  = (__bf16*)(ws + MB(16));
    __bf16* qkv    = (__bf16*)(ws + MB(17));
    __bf16* qbf    = (__bf16*)(ws + MB(41));
    __bf16* kbf    = (__bf16*)(ws + MB(49));
    __bf16* vtbf   = xbf;     // xbf dead after QKV GEMM
    __bf16* obuf   = qkv;     // qkv dead after rope_rms_bf + vconv

    f32_to_bf16<<<(M_ * D_) / (256 * 8), 256, 0, stream>>>(x, xbf);
    wt_conv<<<dim3(16, 16), 256, 0, stream>>>(Wq, wqkv_t,                   D_, D_);
    wt_conv<<<dim3(16, 16), 256, 0, stream>>>(Wk, wqkv_t + 1024 * 1024,     D_, D_);
    wt_conv<<<dim3(16, 16), 256, 0, stream>>>(Wv, wqkv_t + 2 * 1024 * 1024, D_, D_);
    wt_conv<<<dim3(16, 16), 256, 0, stream>>>(Woe, woe_t, D_, D_);
    wt_conv<<<dim3(16, 8),  256, 0, stream>>>(Wod, wod_t, 512, D_);

    gemm_bt<__bf16><<<dim3(3072 / 128, M_ / 128), 256, 0, stream>>>(
        xbf, wqkv_t, qkv, D_, D_, 0, 3072);

    rope_rms_bf<<<(B_ * N_ * H_) / 4, 256, 0, stream>>>(qkv, cs, sn, qbf, kbf);
    vconv<<<dim3(N_ / 64, B_ * H_), 256, 0, stream>>>(qkv, vtbf);

    attn_mfma<<<dim3(N_ / 128, B_ * H_), 256, 0, stream>>>(qbf, kbf, vtbf, obuf);

    gemm_bt<float><<<dim3(D_ / 128, M_ / 128), 256, 0, stream>>>(
        obuf, woe_t, enc_out, D_, D_, 0, D_);
    gemm_bt<float><<<dim3(D_ / 128, M_ / 128), 256, 0, stream>>>(
        obuf, wod_t, dec_out, 512, D_, 512, D_);
}